// Round 13
// baseline (307.106 us; speedup 1.0000x reference)
//
#include <hip/hip_runtime.h>
#include <cstdint>
#include <cstddef>

#define NEG_SLOPE 0.2f

typedef short bf16x8 __attribute__((ext_vector_type(8)));
typedef float f32x4 __attribute__((ext_vector_type(4)));
typedef float f32x2 __attribute__((ext_vector_type(2)));

__device__ __forceinline__ unsigned short f2bf(float f) {
  unsigned u = __float_as_uint(f);
  u = u + 0x7FFFu + ((u >> 16) & 1u);
  return (unsigned short)(u >> 16);
}
__device__ __forceinline__ float bf2f(unsigned short b) {
  return __uint_as_float((unsigned)b << 16);
}
__device__ __forceinline__ f32x2 unpk(unsigned xv) {
  f32x2 r;
  r.x = __uint_as_float(xv << 16);
  r.y = __uint_as_float(xv & 0xFFFF0000u);
  return r;
}
// wave-uniform broadcast of lane l's float (l compile-time or SGPR)
__device__ __forceinline__ float rlf(float v, int l) {
  return __uint_as_float(
      (unsigned)__builtin_amdgcn_readlane((int)__float_as_uint(v), l));
}

// ======================================================================
// P1: all independent prep, partitioned by blockIdx.
// count_dst also records each edge's slot position (atomic return) in
// posb -- removes the second atomic pass entirely.
// ======================================================================
__global__ __launch_bounds__(256) void prep_all(
    const int* __restrict__ ei, int* __restrict__ counts,
    int* __restrict__ posb,
    const float* __restrict__ x, unsigned short* __restrict__ xb,
    const float* __restrict__ W1, const float* __restrict__ att_s1,
    const float* __restrict__ att_d1, unsigned short* __restrict__ AsAdT,
    unsigned short* __restrict__ WbT,
    const float* __restrict__ W2, unsigned short* __restrict__ W2t,
    const float* __restrict__ att_s2, const float* __restrict__ att_d2,
    float* __restrict__ AsAd2,
    int E, int ET, int N, int B0, int B1) {
  int b = blockIdx.x, tid = threadIdx.x;
  if (b < B0) {  // count_dst + slot position
    int i = b * 256 + tid;
    if (i < ET) {
      int dst = (i < E) ? ei[E + i] : (i - E);
      int pos = atomicAdd(&counts[dst], 1);
      posb[i] = pos;
    }
    return;
  }
  b -= B0;
  if (b < B1) {  // cast x -> xb
    int i = b * 256 + tid;
    if (i < N * 32) {
      float4 v = ((const float4*)x)[i];
      ushort4 o;
      o.x = f2bf(v.x); o.y = f2bf(v.y); o.z = f2bf(v.z); o.w = f2bf(v.w);
      ((ushort4*)xb)[i] = o;
    }
    return;
  }
  b -= B1;
  if (b < 8) {  // AsAdT[16][128]
    int i = b * 256 + tid;
    int o = i >> 7, k = i & 127, h = o & 7;
    const float* att = (o < 8) ? att_s1 : att_d1;
    float s = 0.f;
    for (int c = 0; c < 64; c++) s += W1[(size_t)k * 512 + h * 64 + c] * att[h * 64 + c];
    AsAdT[i] = f2bf(s);
    return;
  }
  b -= 8;
  if (b < 256) {  // WbT[64][1024]: WbT[o][h*128+c] = W1[c][h*64+o]
    int i = b * 256 + tid;
    int o = i >> 10, k = i & 1023, h = k >> 7, c = k & 127;
    WbT[i] = f2bf(W1[(size_t)c * 512 + h * 64 + o]);
    return;
  }
  b -= 256;
  if (b < 16) {  // W2t[64][64]: W2t[nn][k] = W2[k][nn]
    int i = b * 256 + tid;
    if (i < 64 * 64) {
      int k = i >> 6, nn = i & 63;
      W2t[(size_t)nn * 64 + k] = f2bf(W2[i]);
    }
    return;
  }
  // AsAd2[2][64]
  {
    int i = tid;
    if (i < 128) {
      int o = i >> 6, k = i & 63;
      const float* att = (o == 0) ? att_s2 : att_d2;
      float s = 0.f;
      for (int c = 0; c < 64; c++) s += W2[(size_t)k * 64 + c] * att[c];
      AsAd2[i] = s;
    }
  }
}

// ======================================================================
// P2: block 0 = single-block scan; blocks 1.. = layer-1 attention dots.
// ======================================================================
__global__ __launch_bounds__(1024) void scan_dots(
    const int* __restrict__ counts, int* __restrict__ offsets,
    const unsigned short* __restrict__ xb, const unsigned short* __restrict__ AsAdT,
    float* __restrict__ asd, int n) {
  if (blockIdx.x == 0) {
    __shared__ int sums[1024];
    int t = threadIdx.x;
    int chunk = (n + 1023) >> 10;
    int start = t * chunk;
    int end = min(start + chunk, n);
    int s = 0;
    for (int i = start; i < end; i++) s += counts[i];
    sums[t] = s;
    __syncthreads();
    for (int off = 1; off < 1024; off <<= 1) {
      int v = (t >= off) ? sums[t - off] : 0;
      __syncthreads();
      sums[t] += v;
      __syncthreads();
    }
    int run = sums[t] - s;
    for (int i = start; i < end; i++) { offsets[i] = run; run += counts[i]; }
    if (t == 1023) offsets[n] = sums[1023];
    return;
  }
  int tid = threadIdx.x;
  int wave = tid >> 6, lane = tid & 63;
  int q = lane >> 4, t = lane & 15;
  int row0 = (blockIdx.x - 1) * 256 + wave * 16;
  int arow = row0 + t; if (arow > n - 1) arow = n - 1;
  const bf16x8* aptr = (const bf16x8*)(xb + (size_t)arow * 128);
  const bf16x8* bptr = (const bf16x8*)(AsAdT + t * 128);
  f32x4 acc = (f32x4){0.f, 0.f, 0.f, 0.f};
  #pragma unroll
  for (int s = 0; s < 4; s++)
    acc = __builtin_amdgcn_mfma_f32_16x16x32_bf16(aptr[s * 4 + q], bptr[s * 4 + q],
                                                  acc, 0, 0, 0);
  #pragma unroll
  for (int r = 0; r < 4; r++) {
    int row = row0 + q * 4 + r;
    if (row < n) asd[row * 16 + t] = acc[r];
  }
}

// ======================================================================
// P3: CSR fill, atomic-free (slot = offsets[dst] + posb[i]).
// ======================================================================
__global__ __launch_bounds__(256) void fill_csr(
    const int* __restrict__ ei, const int* __restrict__ offsets,
    const int* __restrict__ posb, int* __restrict__ srcs, int E, int ET) {
  int i = blockIdx.x * 256 + threadIdx.x;
  if (i >= ET) return;
  int src, dst;
  if (i < E) { src = ei[i]; dst = ei[E + i]; } else { src = dst = i - E; }
  srcs[offsets[dst] + posb[i]] = src;
}

// consume 4 register rows (slots K0..K0+3) with readlane weight broadcasts
#define CONSUME4R(RV, K0, W, ACC)                                     \
  _Pragma("unroll")                                                   \
  for (int k = K0; k < K0 + 4; k++) {                                 \
    f32x2 x2 = unpk(RV[k]);                                           \
    ACC[0] += x2 * rlf(W, (k & 7) * 8 + 0);                           \
    ACC[1] += x2 * rlf(W, (k & 7) * 8 + 1);                           \
    ACC[2] += x2 * rlf(W, (k & 7) * 8 + 2);                           \
    ACC[3] += x2 * rlf(W, (k & 7) * 8 + 3);                           \
    ACC[4] += x2 * rlf(W, (k & 7) * 8 + 4);                           \
    ACC[5] += x2 * rlf(W, (k & 7) * 8 + 5);                           \
    ACC[6] += x2 * rlf(W, (k & 7) * 8 + 6);                           \
    ACC[7] += x2 * rlf(W, (k & 7) * 8 + 7);                           \
  }

// ======================================================================
// P4: fused layer-1 aggregation + GEMM + layer-2 dots. (R12 structure --
// best measured.)  Epilogue now computes only the d-dot (ad2); the
// s-dot is recomputed in agg2 from the gathered zb rows, so as2 and
// its atomics are deleted.
// ======================================================================
__global__ __launch_bounds__(1024, 8) void agg1_gemm(
    const int* __restrict__ offsets, const int* __restrict__ srcs,
    const float* __restrict__ asd, const unsigned short* __restrict__ xb,
    const unsigned short* __restrict__ WbT, const float* __restrict__ b1,
    const float* __restrict__ AsAd2, unsigned short* __restrict__ zb,
    float* __restrict__ ad2, int N) {
  __shared__ unsigned short sh[16 * 1032];  // z-tile, stride 1032 (conflict-free)
  int tid = threadIdx.x;
  int wv = tid >> 6, lane = tid & 63;
  int nb = blockIdx.x;
  {
    int node = nb * 16 + wv;
    f32x2 acc[8];
    #pragma unroll
    for (int h = 0; h < 8; h++) acc[h] = (f32x2){0.f, 0.f};
    float wsl = 0.f;
    int beg = offsets[node], end = offsets[node + 1];
    int jl = end - 1;                       // deg >= 1 (self-loop)
    float adv = asd[(size_t)node * 16 + 8 + (lane & 7)];  // dst dots
    for (int cb = beg; cb < end; cb += 16) {
      int cnt = min(16, end - cb);
      // per-chunk metadata: lane&15 = edge id (feeds readlane row bcast)
      int sAll = srcs[min(cb + (lane & 15), jl)];
      int swa = srcs[min(cb + (lane >> 3), jl)];
      float asva = asd[(size_t)(unsigned)swa * 16 + (lane & 7)];
      float asvb = 0.f;
      if (cnt > 8) {
        int swb = srcs[min(cb + 8 + (lane >> 3), jl)];
        asvb = asd[(size_t)(unsigned)swb * 16 + (lane & 7)];
      }
      // register gather: one coalesced dword per edge row; quarter-
      // granularity wave-uniform guards (loads match consume exactly)
      unsigned rva[8], rvb[8];
      #pragma unroll
      for (int k = 0; k < 4; k++) {
        int se = __builtin_amdgcn_readlane(sAll, k);
        rva[k] = *(const unsigned*)&xb[(size_t)(unsigned)se * 128 + 2 * lane];
      }
      if (cnt > 4) {
        #pragma unroll
        for (int k = 4; k < 8; k++) {
          int se = __builtin_amdgcn_readlane(sAll, k);
          rva[k] = *(const unsigned*)&xb[(size_t)(unsigned)se * 128 + 2 * lane];
        }
      }
      if (cnt > 8) {
        #pragma unroll
        for (int k = 0; k < 4; k++) {
          int se = __builtin_amdgcn_readlane(sAll, k + 8);
          rvb[k] = *(const unsigned*)&xb[(size_t)(unsigned)se * 128 + 2 * lane];
        }
      }
      if (cnt > 12) {
        #pragma unroll
        for (int k = 4; k < 8; k++) {
          int se = __builtin_amdgcn_readlane(sAll, k + 8);
          rvb[k] = *(const unsigned*)&xb[(size_t)(unsigned)se * 128 + 2 * lane];
        }
      }
      // weights (lane = edge*8+head layout), zero-padded
      float wa, wb = 0.f;
      {
        float v = asva + adv;
        v = (v > 0.f) ? v : NEG_SLOPE * v;
        wa = (cb + (lane >> 3) < end) ? __expf(v) : 0.f;
      }
      if (cnt > 8) {
        float v = asvb + adv;
        v = (v > 0.f) ? v : NEG_SLOPE * v;
        wb = (cb + 8 + (lane >> 3) < end) ? __expf(v) : 0.f;
      }
      wsl += wa + wb;                       // per-lane denominator partial
      // consume with the SAME guards as the loads
      CONSUME4R(rva, 0, wa, acc);
      if (cnt > 4) { CONSUME4R(rva, 4, wa, acc); }
      if (cnt > 8) { CONSUME4R(rvb, 0, wb, acc); }
      if (cnt > 12) { CONSUME4R(rvb, 4, wb, acc); }
    }
    // denominator: sum the 8 lanes sharing (lane&7); lane h holds ws[h]
    wsl += __shfl_xor(wsl, 8, 64);
    wsl += __shfl_xor(wsl, 16, 64);
    wsl += __shfl_xor(wsl, 32, 64);
    #pragma unroll
    for (int h = 0; h < 8; h++) {
      float tot = rlf(wsl, h);
      float iv = 0.125f / tot;  // head-mean folded in
      unsigned o = (unsigned)f2bf(acc[h].x * iv) | ((unsigned)f2bf(acc[h].y * iv) << 16);
      *(unsigned*)&sh[wv * 1032 + h * 128 + 2 * lane] = o;
    }
  }
  __syncthreads();
  if (wv < 4) {
    int q = lane >> 4, t = lane & 15;
    f32x4 acc4 = (f32x4){0.f, 0.f, 0.f, 0.f};
    const unsigned short* bbase = WbT + (size_t)(wv * 16 + t) * 1024;
    #pragma unroll 8
    for (int s = 0; s < 32; s++) {
      bf16x8 af = *(const bf16x8*)&sh[t * 1032 + s * 32 + q * 8];
      bf16x8 bf = *(const bf16x8*)&bbase[s * 32 + q * 8];
      acc4 = __builtin_amdgcn_mfma_f32_16x16x32_bf16(af, bf, acc4, 0, 0, 0);
    }
    int col = wv * 16 + t;
    float bias = b1[col];
    float vd = AsAd2[64 + col];
    #pragma unroll
    for (int r = 0; r < 4; r++) {
      int row = q * 4 + r;
      int node = nb * 16 + row;
      float v = acc4[r] + bias;
      v = (v > 0.f) ? v : (__expf(v) - 1.f);  // ELU
      zb[(size_t)node * 64 + col] = f2bf(v);
      float d = v * vd;
      #pragma unroll
      for (int off = 1; off < 16; off <<= 1) {
        d += __shfl_xor(d, off, 64);
      }
      if (t == 0) {
        atomicAdd(&ad2[node], d);
      }
    }
  }
}

// ======================================================================
// P5: fused layer-2 aggregation + GEMM(W2) + bias -> out.
// The per-edge as2[src] gather (1 line/edge, 33% of this kernel's line
// budget) is DELETED: as2 is recomputed in-register from the gathered
// zb row -- lane holds channels 2l,2l+1, partial dot with AsAd2, then
// a 5-step 32-lane xor-reduce.  Weight compute is fused into consume.
// ======================================================================
__global__ __launch_bounds__(1024, 8) void agg2_gemm(
    const int* __restrict__ offsets, const int* __restrict__ srcs,
    const float* __restrict__ ad2, const unsigned short* __restrict__ zb,
    const unsigned short* __restrict__ W2t, const float* __restrict__ AsAd2,
    const float* __restrict__ b2, float* __restrict__ out, int N) {
  __shared__ unsigned short sh[16 * 72];
  int tid = threadIdx.x;
  int wv = tid >> 6, lane = tid & 63;
  int nb = blockIdx.x;
  {
    int node = nb * 16 + wv;
    int half = lane >> 5;                   // 0: even edges, 1: odd edges
    int l2 = lane & 31;
    // per-lane slice of the layer-2 s-attention vector
    f32x2 vsv = *(const f32x2*)&AsAd2[2 * l2];
    float adv = ad2[node];
    int beg = offsets[node], end = offsets[node + 1];
    int jl = end - 1;                        // deg >= 1 (self-loop)
    f32x2 acc = (f32x2){0.f, 0.f};
    float wsl = 0.f;
    for (int cb = beg; cb < end; cb += 16) {
      int cnt = min(16, end - cb);
      int sAll = srcs[min(cb + (lane & 15), jl)];
      // register gather: 2 zb rows per coalesced load; quarter guards
      unsigned rv[8];
      #pragma unroll
      for (int k = 0; k < 2; k++) {
        int s0 = __builtin_amdgcn_readlane(sAll, 2 * k);
        int s1 = __builtin_amdgcn_readlane(sAll, 2 * k + 1);
        int se = half ? s1 : s0;
        rv[k] = *(const unsigned*)&zb[(size_t)(unsigned)se * 64 + 2 * l2];
      }
      if (cnt > 4) {
        #pragma unroll
        for (int k = 2; k < 4; k++) {
          int s0 = __builtin_amdgcn_readlane(sAll, 2 * k);
          int s1 = __builtin_amdgcn_readlane(sAll, 2 * k + 1);
          int se = half ? s1 : s0;
          rv[k] = *(const unsigned*)&zb[(size_t)(unsigned)se * 64 + 2 * l2];
        }
      }
      if (cnt > 8) {
        #pragma unroll
        for (int k = 4; k < 6; k++) {
          int s0 = __builtin_amdgcn_readlane(sAll, 2 * k);
          int s1 = __builtin_amdgcn_readlane(sAll, 2 * k + 1);
          int se = half ? s1 : s0;
          rv[k] = *(const unsigned*)&zb[(size_t)(unsigned)se * 64 + 2 * l2];
        }
      }
      if (cnt > 12) {
        #pragma unroll
        for (int k = 6; k < 8; k++) {
          int s0 = __builtin_amdgcn_readlane(sAll, 2 * k);
          int s1 = __builtin_amdgcn_readlane(sAll, 2 * k + 1);
          int se = half ? s1 : s0;
          rv[k] = *(const unsigned*)&zb[(size_t)(unsigned)se * 64 + 2 * l2];
        }
      }
      // fused: recompute as2 (32-lane dot reduce), weight, consume.
      // each half handles edge 2k+half of the chunk.
      #define A2_STEP(k)                                                  \
        {                                                                 \
          f32x2 x2 = unpk(rv[k]);                                         \
          float p = x2.x * vsv.x + x2.y * vsv.y;                          \
          p += __shfl_xor(p, 1, 64);                                      \
          p += __shfl_xor(p, 2, 64);                                      \
          p += __shfl_xor(p, 4, 64);                                      \
          p += __shfl_xor(p, 8, 64);                                      \
          p += __shfl_xor(p, 16, 64);                                     \
          float v = p + adv;                                              \
          v = (v > 0.f) ? v : NEG_SLOPE * v;                              \
          float w = (cb + 2 * (k) + half < end) ? __expf(v) : 0.f;        \
          acc += x2 * w;                                                  \
          if (l2 == 0) wsl += w;                                          \
        }
      A2_STEP(0) A2_STEP(1)
      if (cnt > 4) { A2_STEP(2) A2_STEP(3) }
      if (cnt > 8) { A2_STEP(4) A2_STEP(5) }
      if (cnt > 12) { A2_STEP(6) A2_STEP(7) }
      #undef A2_STEP
    }
    // denominator: lanes 0 and 32 hold the two halves' partials
    wsl += __shfl_xor(wsl, 32, 64);
    float tot = rlf(wsl, 0);
    // fold odd-edge half into even half
    acc.x += __shfl_xor(acc.x, 32, 64);
    acc.y += __shfl_xor(acc.y, 32, 64);
    if (lane < 32) {
      float inv = 1.f / tot;
      unsigned o = (unsigned)f2bf(acc.x * inv) | ((unsigned)f2bf(acc.y * inv) << 16);
      *(unsigned*)&sh[wv * 72 + 2 * lane] = o;
    }
  }
  __syncthreads();
  if (wv < 4) {
    int q = lane >> 4, t = lane & 15;
    f32x4 acc4 = (f32x4){0.f, 0.f, 0.f, 0.f};
    const unsigned short* bbase = W2t + (size_t)(wv * 16 + t) * 64;
    #pragma unroll
    for (int s = 0; s < 2; s++) {
      bf16x8 af = *(const bf16x8*)&sh[t * 72 + s * 32 + q * 8];
      bf16x8 bf = *(const bf16x8*)&bbase[s * 32 + q * 8];
      acc4 = __builtin_amdgcn_mfma_f32_16x16x32_bf16(af, bf, acc4, 0, 0, 0);
    }
    int col = wv * 16 + t;
    float bias = b2[col];
    #pragma unroll
    for (int r = 0; r < 4; r++) {
      int node = nb * 16 + q * 4 + r;
      if (node < N) out[(size_t)node * 64 + col] = acc4[r] + bias;
    }
  }
}

// ---------- host launch ----------
extern "C" void kernel_launch(void* const* d_in, const int* in_sizes, int n_in,
                              void* d_out, int out_size, void* d_ws, size_t ws_size,
                              hipStream_t stream) {
  const int IN = 128;
  const int N = in_sizes[0] / IN;      // 50000
  const int E = in_sizes[1] / 2;       // 400000
  const int ET = E + N;

  const float* x        = (const float*)d_in[0];
  const int*   ei       = (const int*)d_in[1];
  const float* W1       = (const float*)d_in[2];
  const float* att_src1 = (const float*)d_in[3];
  const float* att_dst1 = (const float*)d_in[4];
  const float* b1       = (const float*)d_in[5];
  const float* W2       = (const float*)d_in[6];
  const float* att_src2 = (const float*)d_in[7];
  const float* att_dst2 = (const float*)d_in[8];
  const float* b2       = (const float*)d_in[9];
  float* out = (float*)d_out;

  char* base = (char*)d_ws;
  size_t off = 0;
  auto alloc = [&](size_t bytes) -> char* {
    char* p = base + off;
    off = (off + bytes + 255) & ~(size_t)255;
    return p;
  };
  unsigned short* xb    = (unsigned short*)alloc((size_t)N * 128 * 2);
  unsigned short* AsAdT = (unsigned short*)alloc((size_t)16 * 128 * 2);
  unsigned short* WbT   = (unsigned short*)alloc((size_t)64 * 1024 * 2);
  unsigned short* W2t   = (unsigned short*)alloc((size_t)64 * 64 * 2);
  unsigned short* zb    = (unsigned short*)alloc((size_t)N * 64 * 2);
  float* AsAd2 = (float*)alloc((size_t)128 * 4);
  float* asd1  = (float*)alloc((size_t)N * 16 * 4);
  int* offsets = (int*)alloc((size_t)(N + 1) * 4);
  int* srcs    = (int*)alloc((size_t)ET * 4);
  int* posb    = (int*)alloc((size_t)ET * 4);
  char* zero_begin = base + off;
  int* counts  = (int*)alloc((size_t)N * 4);
  float* a_d2  = (float*)alloc((size_t)N * 4);
  char* zero_end = base + off;

  hipMemsetAsync(zero_begin, 0, (size_t)(zero_end - zero_begin), stream);

  const int TB = 256;
  auto cdiv = [](int a, int b) { return (a + b - 1) / b; };

  int B0 = cdiv(ET, TB);
  int B1 = cdiv(N * 32, TB);
  prep_all<<<B0 + B1 + 8 + 256 + 16 + 1, TB, 0, stream>>>(
      ei, counts, posb, x, xb, W1, att_src1, att_dst1, AsAdT, WbT, W2, W2t,
      att_src2, att_dst2, AsAd2, E, ET, N, B0, B1);

  scan_dots<<<1 + cdiv(N, 256), 1024, 0, stream>>>(counts, offsets, xb, AsAdT,
                                                   asd1, N);

  fill_csr<<<cdiv(ET, TB), TB, 0, stream>>>(ei, offsets, posb, srcs, E, ET);

  agg1_gemm<<<cdiv(N, 16), 1024, 0, stream>>>(offsets, srcs, asd1, xb, WbT, b1,
                                              AsAd2, zb, a_d2, N);

  agg2_gemm<<<cdiv(N, 16), 1024, 0, stream>>>(offsets, srcs, a_d2, zb, W2t,
                                              AsAd2, b2, out, N);
}

// Round 15
// 301.776 us; speedup vs baseline: 1.0177x; 1.0177x over previous
//
#include <hip/hip_runtime.h>
#include <cstdint>
#include <cstddef>

#define NEG_SLOPE 0.2f

typedef short bf16x8 __attribute__((ext_vector_type(8)));
typedef float f32x4 __attribute__((ext_vector_type(4)));
typedef float f32x2 __attribute__((ext_vector_type(2)));

__device__ __forceinline__ unsigned short f2bf(float f) {
  unsigned u = __float_as_uint(f);
  u = u + 0x7FFFu + ((u >> 16) & 1u);
  return (unsigned short)(u >> 16);
}
__device__ __forceinline__ float bf2f(unsigned short b) {
  return __uint_as_float((unsigned)b << 16);
}
__device__ __forceinline__ f32x2 unpk(unsigned xv) {
  f32x2 r;
  r.x = __uint_as_float(xv << 16);
  r.y = __uint_as_float(xv & 0xFFFF0000u);
  return r;
}
// wave-uniform broadcast of lane l's float (l compile-time or SGPR)
__device__ __forceinline__ float rlf(float v, int l) {
  return __uint_as_float(
      (unsigned)__builtin_amdgcn_readlane((int)__float_as_uint(v), l));
}

// ======================================================================
// P1: all independent prep, partitioned by blockIdx.
// count_dst also records each edge's slot position (atomic return) in
// posb -- removes the second atomic pass entirely.
// ======================================================================
__global__ __launch_bounds__(256) void prep_all(
    const int* __restrict__ ei, int* __restrict__ counts,
    int* __restrict__ posb,
    const float* __restrict__ x, unsigned short* __restrict__ xb,
    const float* __restrict__ W1, const float* __restrict__ att_s1,
    const float* __restrict__ att_d1, unsigned short* __restrict__ AsAdT,
    unsigned short* __restrict__ WbT,
    const float* __restrict__ W2, unsigned short* __restrict__ W2t,
    const float* __restrict__ att_s2, const float* __restrict__ att_d2,
    float* __restrict__ AsAd2,
    int E, int ET, int N, int B0, int B1) {
  int b = blockIdx.x, tid = threadIdx.x;
  if (b < B0) {  // count_dst + slot position
    int i = b * 256 + tid;
    if (i < ET) {
      int dst = (i < E) ? ei[E + i] : (i - E);
      int pos = atomicAdd(&counts[dst], 1);
      posb[i] = pos;
    }
    return;
  }
  b -= B0;
  if (b < B1) {  // cast x -> xb
    int i = b * 256 + tid;
    if (i < N * 32) {
      float4 v = ((const float4*)x)[i];
      ushort4 o;
      o.x = f2bf(v.x); o.y = f2bf(v.y); o.z = f2bf(v.z); o.w = f2bf(v.w);
      ((ushort4*)xb)[i] = o;
    }
    return;
  }
  b -= B1;
  if (b < 8) {  // AsAdT[16][128]
    int i = b * 256 + tid;
    int o = i >> 7, k = i & 127, h = o & 7;
    const float* att = (o < 8) ? att_s1 : att_d1;
    float s = 0.f;
    for (int c = 0; c < 64; c++) s += W1[(size_t)k * 512 + h * 64 + c] * att[h * 64 + c];
    AsAdT[i] = f2bf(s);
    return;
  }
  b -= 8;
  if (b < 256) {  // WbT[64][1024]: WbT[o][h*128+c] = W1[c][h*64+o]
    int i = b * 256 + tid;
    int o = i >> 10, k = i & 1023, h = k >> 7, c = k & 127;
    WbT[i] = f2bf(W1[(size_t)c * 512 + h * 64 + o]);
    return;
  }
  b -= 256;
  if (b < 16) {  // W2t[64][64]: W2t[nn][k] = W2[k][nn]
    int i = b * 256 + tid;
    if (i < 64 * 64) {
      int k = i >> 6, nn = i & 63;
      W2t[(size_t)nn * 64 + k] = f2bf(W2[i]);
    }
    return;
  }
  // AsAd2[2][64]
  {
    int i = tid;
    if (i < 128) {
      int o = i >> 6, k = i & 63;
      const float* att = (o == 0) ? att_s2 : att_d2;
      float s = 0.f;
      for (int c = 0; c < 64; c++) s += W2[(size_t)k * 64 + c] * att[c];
      AsAd2[i] = s;
    }
  }
}

// ======================================================================
// P2: block 0 = single-block scan; blocks 1.. = layer-1 attention dots.
// ======================================================================
__global__ __launch_bounds__(1024) void scan_dots(
    const int* __restrict__ counts, int* __restrict__ offsets,
    const unsigned short* __restrict__ xb, const unsigned short* __restrict__ AsAdT,
    float* __restrict__ asd, int n) {
  if (blockIdx.x == 0) {
    __shared__ int sums[1024];
    int t = threadIdx.x;
    int chunk = (n + 1023) >> 10;
    int start = t * chunk;
    int end = min(start + chunk, n);
    int s = 0;
    for (int i = start; i < end; i++) s += counts[i];
    sums[t] = s;
    __syncthreads();
    for (int off = 1; off < 1024; off <<= 1) {
      int v = (t >= off) ? sums[t - off] : 0;
      __syncthreads();
      sums[t] += v;
      __syncthreads();
    }
    int run = sums[t] - s;
    for (int i = start; i < end; i++) { offsets[i] = run; run += counts[i]; }
    if (t == 1023) offsets[n] = sums[1023];
    return;
  }
  int tid = threadIdx.x;
  int wave = tid >> 6, lane = tid & 63;
  int q = lane >> 4, t = lane & 15;
  int row0 = (blockIdx.x - 1) * 256 + wave * 16;
  int arow = row0 + t; if (arow > n - 1) arow = n - 1;
  const bf16x8* aptr = (const bf16x8*)(xb + (size_t)arow * 128);
  const bf16x8* bptr = (const bf16x8*)(AsAdT + t * 128);
  f32x4 acc = (f32x4){0.f, 0.f, 0.f, 0.f};
  #pragma unroll
  for (int s = 0; s < 4; s++)
    acc = __builtin_amdgcn_mfma_f32_16x16x32_bf16(aptr[s * 4 + q], bptr[s * 4 + q],
                                                  acc, 0, 0, 0);
  #pragma unroll
  for (int r = 0; r < 4; r++) {
    int row = row0 + q * 4 + r;
    if (row < n) asd[row * 16 + t] = acc[r];
  }
}

// ======================================================================
// P3: CSR fill, atomic-free (slot = offsets[dst] + posb[i]).
// ======================================================================
__global__ __launch_bounds__(256) void fill_csr(
    const int* __restrict__ ei, const int* __restrict__ offsets,
    const int* __restrict__ posb, int* __restrict__ srcs, int E, int ET) {
  int i = blockIdx.x * 256 + threadIdx.x;
  if (i >= ET) return;
  int src, dst;
  if (i < E) { src = ei[i]; dst = ei[E + i]; } else { src = dst = i - E; }
  srcs[offsets[dst] + posb[i]] = src;
}

// consume 4 register rows (slots K0..K0+3) with readlane weight broadcasts
#define CONSUME4R(RV, K0, W, ACC)                                     \
  _Pragma("unroll")                                                   \
  for (int k = K0; k < K0 + 4; k++) {                                 \
    f32x2 x2 = unpk(RV[k]);                                           \
    ACC[0] += x2 * rlf(W, (k & 7) * 8 + 0);                           \
    ACC[1] += x2 * rlf(W, (k & 7) * 8 + 1);                           \
    ACC[2] += x2 * rlf(W, (k & 7) * 8 + 2);                           \
    ACC[3] += x2 * rlf(W, (k & 7) * 8 + 3);                           \
    ACC[4] += x2 * rlf(W, (k & 7) * 8 + 4);                           \
    ACC[5] += x2 * rlf(W, (k & 7) * 8 + 5);                           \
    ACC[6] += x2 * rlf(W, (k & 7) * 8 + 6);                           \
    ACC[7] += x2 * rlf(W, (k & 7) * 8 + 7);                           \
  }

// ======================================================================
// P4: fused layer-1 aggregation + GEMM + layer-2 dots. (R12 structure --
// best measured.)  Epilogue change: the s/d-dot cross-wave combine now
// uses a 512-B LDS reduction + plain coalesced stores instead of 100k
// device atomics (all 4 partials live in this block; N%16==0 so every
// node is written exactly once).
// ======================================================================
__global__ __launch_bounds__(1024, 8) void agg1_gemm(
    const int* __restrict__ offsets, const int* __restrict__ srcs,
    const float* __restrict__ asd, const unsigned short* __restrict__ xb,
    const unsigned short* __restrict__ WbT, const float* __restrict__ b1,
    const float* __restrict__ AsAd2, unsigned short* __restrict__ zb,
    float* __restrict__ as2, float* __restrict__ ad2, int N) {
  __shared__ unsigned short sh[16 * 1032];  // z-tile, stride 1032 (conflict-free)
  __shared__ float sred[4][16], dred[4][16];
  int tid = threadIdx.x;
  int wv = tid >> 6, lane = tid & 63;
  int nb = blockIdx.x;
  {
    int node = nb * 16 + wv;
    f32x2 acc[8];
    #pragma unroll
    for (int h = 0; h < 8; h++) acc[h] = (f32x2){0.f, 0.f};
    float wsl = 0.f;
    int beg = offsets[node], end = offsets[node + 1];
    int jl = end - 1;                       // deg >= 1 (self-loop)
    float adv = asd[(size_t)node * 16 + 8 + (lane & 7)];  // dst dots
    for (int cb = beg; cb < end; cb += 16) {
      int cnt = min(16, end - cb);
      // per-chunk metadata: lane&15 = edge id (feeds readlane row bcast)
      int sAll = srcs[min(cb + (lane & 15), jl)];
      int swa = srcs[min(cb + (lane >> 3), jl)];
      float asva = asd[(size_t)(unsigned)swa * 16 + (lane & 7)];
      float asvb = 0.f;
      if (cnt > 8) {
        int swb = srcs[min(cb + 8 + (lane >> 3), jl)];
        asvb = asd[(size_t)(unsigned)swb * 16 + (lane & 7)];
      }
      // register gather: one coalesced dword per edge row; quarter-
      // granularity wave-uniform guards (loads match consume exactly)
      unsigned rva[8], rvb[8];
      #pragma unroll
      for (int k = 0; k < 4; k++) {
        int se = __builtin_amdgcn_readlane(sAll, k);
        rva[k] = *(const unsigned*)&xb[(size_t)(unsigned)se * 128 + 2 * lane];
      }
      if (cnt > 4) {
        #pragma unroll
        for (int k = 4; k < 8; k++) {
          int se = __builtin_amdgcn_readlane(sAll, k);
          rva[k] = *(const unsigned*)&xb[(size_t)(unsigned)se * 128 + 2 * lane];
        }
      }
      if (cnt > 8) {
        #pragma unroll
        for (int k = 0; k < 4; k++) {
          int se = __builtin_amdgcn_readlane(sAll, k + 8);
          rvb[k] = *(const unsigned*)&xb[(size_t)(unsigned)se * 128 + 2 * lane];
        }
      }
      if (cnt > 12) {
        #pragma unroll
        for (int k = 4; k < 8; k++) {
          int se = __builtin_amdgcn_readlane(sAll, k + 8);
          rvb[k] = *(const unsigned*)&xb[(size_t)(unsigned)se * 128 + 2 * lane];
        }
      }
      // weights (lane = edge*8+head layout), zero-padded
      float wa, wb = 0.f;
      {
        float v = asva + adv;
        v = (v > 0.f) ? v : NEG_SLOPE * v;
        wa = (cb + (lane >> 3) < end) ? __expf(v) : 0.f;
      }
      if (cnt > 8) {
        float v = asvb + adv;
        v = (v > 0.f) ? v : NEG_SLOPE * v;
        wb = (cb + 8 + (lane >> 3) < end) ? __expf(v) : 0.f;
      }
      wsl += wa + wb;                       // per-lane denominator partial
      // consume with the SAME guards as the loads
      CONSUME4R(rva, 0, wa, acc);
      if (cnt > 4) { CONSUME4R(rva, 4, wa, acc); }
      if (cnt > 8) { CONSUME4R(rvb, 0, wb, acc); }
      if (cnt > 12) { CONSUME4R(rvb, 4, wb, acc); }
    }
    // denominator: sum the 8 lanes sharing (lane&7); lane h holds ws[h]
    wsl += __shfl_xor(wsl, 8, 64);
    wsl += __shfl_xor(wsl, 16, 64);
    wsl += __shfl_xor(wsl, 32, 64);
    #pragma unroll
    for (int h = 0; h < 8; h++) {
      float tot = rlf(wsl, h);
      float iv = 0.125f / tot;  // head-mean folded in
      unsigned o = (unsigned)f2bf(acc[h].x * iv) | ((unsigned)f2bf(acc[h].y * iv) << 16);
      *(unsigned*)&sh[wv * 1032 + h * 128 + 2 * lane] = o;
    }
  }
  __syncthreads();
  if (wv < 4) {
    int q = lane >> 4, t = lane & 15;
    f32x4 acc4 = (f32x4){0.f, 0.f, 0.f, 0.f};
    const unsigned short* bbase = WbT + (size_t)(wv * 16 + t) * 1024;
    #pragma unroll 8
    for (int s = 0; s < 32; s++) {
      bf16x8 af = *(const bf16x8*)&sh[t * 1032 + s * 32 + q * 8];
      bf16x8 bf = *(const bf16x8*)&bbase[s * 32 + q * 8];
      acc4 = __builtin_amdgcn_mfma_f32_16x16x32_bf16(af, bf, acc4, 0, 0, 0);
    }
    int col = wv * 16 + t;
    float bias = b1[col];
    float vs = AsAd2[col], vd = AsAd2[64 + col];
    #pragma unroll
    for (int r = 0; r < 4; r++) {
      int row = q * 4 + r;
      int node = nb * 16 + row;
      float v = acc4[r] + bias;
      v = (v > 0.f) ? v : (__expf(v) - 1.f);  // ELU
      zb[(size_t)node * 64 + col] = f2bf(v);
      float s = v * vs, d = v * vd;
      #pragma unroll
      for (int off = 1; off < 16; off <<= 1) {
        s += __shfl_xor(s, off, 64);
        d += __shfl_xor(d, off, 64);
      }
      if (t == 0) {           // lanes 0,16,32,48 -> rows q*4+r
        sred[wv][row] = s;
        dred[wv][row] = d;
      }
    }
  }
  __syncthreads();
  if (tid < 16) {
    int node = nb * 16 + tid;
    as2[node] = sred[0][tid] + sred[1][tid] + sred[2][tid] + sred[3][tid];
    ad2[node] = dred[0][tid] + dred[1][tid] + dred[2][tid] + dred[3][tid];
  }
}

// ======================================================================
// P5: fused layer-2 aggregation + GEMM(W2) + bias -> out. (R12 version
// verbatim -- the best-measured config.)  Register gather: zb row =
// 128B = 32 lanes x 4B, two rows per coalesced load; load groups and
// consume groups share identical wave-uniform quarter guards.
// ======================================================================
__global__ __launch_bounds__(1024, 8) void agg2_gemm(
    const int* __restrict__ offsets, const int* __restrict__ srcs,
    const float* __restrict__ as2, const float* __restrict__ ad2,
    const unsigned short* __restrict__ zb, const unsigned short* __restrict__ W2t,
    const float* __restrict__ b2, float* __restrict__ out, int N) {
  __shared__ unsigned short sh[16 * 72];
  int tid = threadIdx.x;
  int wv = tid >> 6, lane = tid & 63;
  int nb = blockIdx.x;
  {
    int node = nb * 16 + wv;
    int half = lane >> 5;                   // 0: even edges, 1: odd edges
    float adv = ad2[node];
    int beg = offsets[node], end = offsets[node + 1];
    int jl = end - 1;                        // deg >= 1 (self-loop)
    f32x2 acc = (f32x2){0.f, 0.f};
    float wsl = 0.f;
    for (int cb = beg; cb < end; cb += 16) {
      int cnt = min(16, end - cb);
      int sAll = srcs[min(cb + (lane & 15), jl)];
      float asv = as2[sAll];                 // weight source (lane&15 = edge)
      // register gather: 2 zb rows per coalesced load; quarter guards
      unsigned rv[8];
      #pragma unroll
      for (int k = 0; k < 2; k++) {
        int s0 = __builtin_amdgcn_readlane(sAll, 2 * k);
        int s1 = __builtin_amdgcn_readlane(sAll, 2 * k + 1);
        int se = half ? s1 : s0;
        rv[k] = *(const unsigned*)&zb[(size_t)(unsigned)se * 64 + 2 * (lane & 31)];
      }
      if (cnt > 4) {
        #pragma unroll
        for (int k = 2; k < 4; k++) {
          int s0 = __builtin_amdgcn_readlane(sAll, 2 * k);
          int s1 = __builtin_amdgcn_readlane(sAll, 2 * k + 1);
          int se = half ? s1 : s0;
          rv[k] = *(const unsigned*)&zb[(size_t)(unsigned)se * 64 + 2 * (lane & 31)];
        }
      }
      if (cnt > 8) {
        #pragma unroll
        for (int k = 4; k < 6; k++) {
          int s0 = __builtin_amdgcn_readlane(sAll, 2 * k);
          int s1 = __builtin_amdgcn_readlane(sAll, 2 * k + 1);
          int se = half ? s1 : s0;
          rv[k] = *(const unsigned*)&zb[(size_t)(unsigned)se * 64 + 2 * (lane & 31)];
        }
      }
      if (cnt > 12) {
        #pragma unroll
        for (int k = 6; k < 8; k++) {
          int s0 = __builtin_amdgcn_readlane(sAll, 2 * k);
          int s1 = __builtin_amdgcn_readlane(sAll, 2 * k + 1);
          int se = half ? s1 : s0;
          rv[k] = *(const unsigned*)&zb[(size_t)(unsigned)se * 64 + 2 * (lane & 31)];
        }
      }
      float v = asv + adv;
      v = (v > 0.f) ? v : NEG_SLOPE * v;
      float wl = (cb + (lane & 15) < end) ? __expf(v) : 0.f;
      if (lane < 16) wsl += wl;              // each edge counted once
      // consume with the SAME guards as the loads
      #pragma unroll
      for (int k = 0; k < 2; k++) {
        float w0 = rlf(wl, 2 * k);
        float w1 = rlf(wl, 2 * k + 1);
        float w = half ? w1 : w0;
        acc += unpk(rv[k]) * w;
      }
      if (cnt > 4) {
        #pragma unroll
        for (int k = 2; k < 4; k++) {
          float w0 = rlf(wl, 2 * k);
          float w1 = rlf(wl, 2 * k + 1);
          float w = half ? w1 : w0;
          acc += unpk(rv[k]) * w;
        }
      }
      if (cnt > 8) {
        #pragma unroll
        for (int k = 4; k < 6; k++) {
          float w0 = rlf(wl, 2 * k);
          float w1 = rlf(wl, 2 * k + 1);
          float w = half ? w1 : w0;
          acc += unpk(rv[k]) * w;
        }
      }
      if (cnt > 12) {
        #pragma unroll
        for (int k = 6; k < 8; k++) {
          float w0 = rlf(wl, 2 * k);
          float w1 = rlf(wl, 2 * k + 1);
          float w = half ? w1 : w0;
          acc += unpk(rv[k]) * w;
        }
      }
    }
    // denominator: total over edges (held in lanes 0-15)
    wsl += __shfl_xor(wsl, 1, 64);
    wsl += __shfl_xor(wsl, 2, 64);
    wsl += __shfl_xor(wsl, 4, 64);
    wsl += __shfl_xor(wsl, 8, 64);
    float tot = rlf(wsl, 0);
    // fold odd-edge half into even half
    acc.x += __shfl_xor(acc.x, 32, 64);
    acc.y += __shfl_xor(acc.y, 32, 64);
    if (lane < 32) {
      float inv = 1.f / tot;
      unsigned o = (unsigned)f2bf(acc.x * inv) | ((unsigned)f2bf(acc.y * inv) << 16);
      *(unsigned*)&sh[wv * 72 + 2 * lane] = o;
    }
  }
  __syncthreads();
  if (wv < 4) {
    int q = lane >> 4, t = lane & 15;
    f32x4 acc4 = (f32x4){0.f, 0.f, 0.f, 0.f};
    const unsigned short* bbase = W2t + (size_t)(wv * 16 + t) * 64;
    #pragma unroll
    for (int s = 0; s < 2; s++) {
      bf16x8 af = *(const bf16x8*)&sh[t * 72 + s * 32 + q * 8];
      bf16x8 bf = *(const bf16x8*)&bbase[s * 32 + q * 8];
      acc4 = __builtin_amdgcn_mfma_f32_16x16x32_bf16(af, bf, acc4, 0, 0, 0);
    }
    int col = wv * 16 + t;
    float bias = b2[col];
    #pragma unroll
    for (int r = 0; r < 4; r++) {
      int node = nb * 16 + q * 4 + r;
      if (node < N) out[(size_t)node * 64 + col] = acc4[r] + bias;
    }
  }
}

// ---------- host launch ----------
extern "C" void kernel_launch(void* const* d_in, const int* in_sizes, int n_in,
                              void* d_out, int out_size, void* d_ws, size_t ws_size,
                              hipStream_t stream) {
  const int IN = 128;
  const int N = in_sizes[0] / IN;      // 50000
  const int E = in_sizes[1] / 2;       // 400000
  const int ET = E + N;

  const float* x        = (const float*)d_in[0];
  const int*   ei       = (const int*)d_in[1];
  const float* W1       = (const float*)d_in[2];
  const float* att_src1 = (const float*)d_in[3];
  const float* att_dst1 = (const float*)d_in[4];
  const float* b1       = (const float*)d_in[5];
  const float* W2       = (const float*)d_in[6];
  const float* att_src2 = (const float*)d_in[7];
  const float* att_dst2 = (const float*)d_in[8];
  const float* b2       = (const float*)d_in[9];
  float* out = (float*)d_out;

  char* base = (char*)d_ws;
  size_t off = 0;
  auto alloc = [&](size_t bytes) -> char* {
    char* p = base + off;
    off = (off + bytes + 255) & ~(size_t)255;
    return p;
  };
  unsigned short* xb    = (unsigned short*)alloc((size_t)N * 128 * 2);
  unsigned short* AsAdT = (unsigned short*)alloc((size_t)16 * 128 * 2);
  unsigned short* WbT   = (unsigned short*)alloc((size_t)64 * 1024 * 2);
  unsigned short* W2t   = (unsigned short*)alloc((size_t)64 * 64 * 2);
  unsigned short* zb    = (unsigned short*)alloc((size_t)N * 64 * 2);
  float* AsAd2 = (float*)alloc((size_t)128 * 4);
  float* asd1  = (float*)alloc((size_t)N * 16 * 4);
  int* offsets = (int*)alloc((size_t)(N + 1) * 4);
  int* srcs    = (int*)alloc((size_t)ET * 4);
  int* posb    = (int*)alloc((size_t)ET * 4);
  float* a_s2  = (float*)alloc((size_t)N * 4);   // plain stores (no memset)
  float* a_d2  = (float*)alloc((size_t)N * 4);
  char* zero_begin = base + off;
  int* counts  = (int*)alloc((size_t)N * 4);
  char* zero_end = base + off;

  hipMemsetAsync(zero_begin, 0, (size_t)(zero_end - zero_begin), stream);

  const int TB = 256;
  auto cdiv = [](int a, int b) { return (a + b - 1) / b; };

  int B0 = cdiv(ET, TB);
  int B1 = cdiv(N * 32, TB);
  prep_all<<<B0 + B1 + 8 + 256 + 16 + 1, TB, 0, stream>>>(
      ei, counts, posb, x, xb, W1, att_src1, att_dst1, AsAdT, WbT, W2, W2t,
      att_src2, att_dst2, AsAd2, E, ET, N, B0, B1);

  scan_dots<<<1 + cdiv(N, 256), 1024, 0, stream>>>(counts, offsets, xb, AsAdT,
                                                   asd1, N);

  fill_csr<<<cdiv(ET, TB), TB, 0, stream>>>(ei, offsets, posb, srcs, E, ET);

  agg1_gemm<<<cdiv(N, 16), 1024, 0, stream>>>(offsets, srcs, asd1, xb, WbT, b1,
                                              AsAd2, zb, a_s2, a_d2, N);

  agg2_gemm<<<cdiv(N, 16), 1024, 0, stream>>>(offsets, srcs, a_s2, a_d2, zb,
                                              W2t, b2, out, N);
}